// Round 1
// baseline (198.971 us; speedup 1.0000x reference)
//
#include <hip/hip_runtime.h>
#include <math.h>

#define N_NODES 2048
#define N_EDGES 4096
#define NBLK 256            // mega-kernel grid: 1 block/CU, co-resident by construction
#define PI_F 3.14159265358979323846f
#define TWO_PI_F 6.28318530717958647692f

// xor-shuffle with DPP fast paths (VALU, no DS pipe):
//   mask 1 -> quad_perm [1,0,3,2] (0xB1)
//   mask 2 -> quad_perm [2,3,0,1] (0x4E)
//   mask 8 -> row_ror:8 (0x128): (lane+8)%16 == lane^8 within each 16-row
// masks 4,16,32 stay on ds_bpermute via __shfl_xor.
template<int M>
__device__ __forceinline__ float shflx(float v) {
    if constexpr (M == 1) {
        return __int_as_float(__builtin_amdgcn_mov_dpp(
            __float_as_int(v), 0xB1, 0xF, 0xF, false));
    } else if constexpr (M == 2) {
        return __int_as_float(__builtin_amdgcn_mov_dpp(
            __float_as_int(v), 0x4E, 0xF, 0xF, false));
    } else if constexpr (M == 8) {
        return __int_as_float(__builtin_amdgcn_mov_dpp(
            __float_as_int(v), 0x128, 0xF, 0xF, false));
    } else {
        return __shfl_xor(v, M, 64);
    }
}

__device__ __forceinline__ float wave_sum(float p) {
    p += shflx<32>(p); p += shflx<16>(p); p += shflx<8>(p);
    p += shflx<4>(p);  p += shflx<2>(p);  p += shflx<1>(p);
    return p;
}

// ---------------- gate helpers ----------------
// Amplitude index = lane*NA + j. j bits = in-register, lane bits above.
// RY pair semantics: new0 = c*s0 - s*s1 ; new1 = s*s0 + c*s1.

template<int NA, int B>
__device__ __forceinline__ void ry_j(float* a, float c, float s) {
#pragma unroll
    for (int j = 0; j < NA; ++j) {
        if ((j & (1 << B)) == 0) {
            int k = j | (1 << B);
            float x0 = a[j], x1 = a[k];
            a[j] = c * x0 - s * x1;
            a[k] = s * x0 + c * x1;
        }
    }
}

// MASK = lane-bit mask of the wire
template<int NA, int MASK>
__device__ __forceinline__ void ry_l(float* a, float c, float s, int lane) {
    float ss = (lane & MASK) ? s : -s;
#pragma unroll
    for (int j = 0; j < NA; ++j) {
        float p = shflx<MASK>(a[j]);
        a[j] = c * a[j] + ss * p;
    }
}

template<int NA, int BC, int BT>
__device__ __forceinline__ void cx_jj(float* a) {   // pure register rename
#pragma unroll
    for (int j = 0; j < NA; ++j) {
        if ((j & (1 << BC)) && !(j & (1 << BT))) {
            int k = j | (1 << BT);
            float t = a[j]; a[j] = a[k]; a[k] = t;
        }
    }
}

template<int NA, int MC, int BT>
__device__ __forceinline__ void cx_lj(float* a, int lane) {   // cndmask only
    bool sel = (lane & MC) != 0;
#pragma unroll
    for (int j = 0; j < NA; ++j) {
        if ((j & (1 << BT)) == 0) {
            int k = j | (1 << BT);
            float t0 = a[j], t1 = a[k];
            a[j] = sel ? t1 : t0;
            a[k] = sel ? t0 : t1;
        }
    }
}

template<int NA, int MC, int MT>
__device__ __forceinline__ void cx_ll(float* a, int lane) {
    bool sel = (lane & MC) != 0;
#pragma unroll
    for (int j = 0; j < NA; ++j) {
        float p = shflx<MT>(a[j]);
        a[j] = sel ? p : a[j];
    }
}

// ---------------- device-scope grid barrier ----------------
// One fresh counter cell per barrier instance (zeroed by k_setup, so the
// harness's workspace re-poison is handled). Release/acquire via
// __threadfence() (agent scope -> L2 wb/inv, cross-XCD safe per G16).
__device__ __forceinline__ void gridbar(int* cell) {
    __syncthreads();
    if (threadIdx.x == 0) {
        __threadfence();                                   // release
        __hip_atomic_fetch_add(cell, 1, __ATOMIC_RELAXED,
                               __HIP_MEMORY_SCOPE_AGENT);
        while (__hip_atomic_load(cell, __ATOMIC_RELAXED,
                                 __HIP_MEMORY_SCOPE_AGENT) < NBLK)
            __builtin_amdgcn_s_sleep(1);
        __threadfence();                                   // acquire
    }
    __syncthreads();
}

// ---------------- setup: H0 + htrig + indices + macc zero + theta trig ----
// One float4-pair per thread (2M threads): measured HBM-bound (r2/r7).
__global__ __launch_bounds__(256) void k_setup(
        const float* __restrict__ X, const float* __restrict__ Ri,
        const float* __restrict__ Ro, const float* __restrict__ W,
        const float* __restrict__ b, const float* __restrict__ te,
        const float* __restrict__ tn,
        int* __restrict__ send, int* __restrict__ recv, float* __restrict__ H,
        float* __restrict__ htrig,
        float* __restrict__ maccA, float* __restrict__ maccB,
        float* __restrict__ trig, int* __restrict__ bar) {
    int tid = blockIdx.x * blockDim.x + threadIdx.x;
    if (tid < N_NODES) {
        float x0 = X[tid*3+0], x1 = X[tid*3+1], x2 = X[tid*3+2];
        float z = x0*W[0] + x1*W[1] + x2*W[2] + b[0];
        float sg = 1.0f / (1.0f + __expf(-z));
        float h = sg * TWO_PI_F;
        H[tid*4+0] = h;
        H[tid*4+1] = x0; H[tid*4+2] = x1; H[tid*4+3] = x2;
        float c0,s0,c1,s1,c2,s2,c3,s3;
        __sincosf(0.5f*h,  &s0, &c0);
        __sincosf(0.5f*x0, &s1, &c1);
        __sincosf(0.5f*x1, &s2, &c2);
        __sincosf(0.5f*x2, &s3, &c3);
        ((float4*)htrig)[tid*2+0] = make_float4(c0, s0, c1, s1);
        ((float4*)htrig)[tid*2+1] = make_float4(c2, s2, c3, s3);
    }
    if (tid < N_NODES * 8) { maccA[tid] = 0.f; maccB[tid] = 0.f; }
    if (tid < 4) bar[tid] = 0;                   // grid-barrier cells
    if (tid >= 4096 && tid < 4096 + 15) {        // edge theta trig
        int i = tid - 4096; float s, c;
        __sincosf(0.5f * te[i], &s, &c);
        trig[i] = c; trig[16 + i] = s;
    }
    if (tid >= 4224 && tid < 4224 + 23) {        // node theta trig
        int i = tid - 4224; float s, c;
        __sincosf(0.5f * tn[i], &s, &c);
        trig[32 + i] = c; trig[56 + i] = s;
    }
    const float4 vi = ((const float4*)Ri)[tid];
    const float4 vo = ((const float4*)Ro)[tid];
    int base = tid * 4;
    int n = base >> 12;             // row (E = 4096)
    int e = base & (N_EDGES - 1);   // col
    if (vi.x != 0.f) recv[e+0] = n;
    if (vi.y != 0.f) recv[e+1] = n;
    if (vi.z != 0.f) recv[e+2] = n;
    if (vi.w != 0.f) recv[e+3] = n;
    if (vo.x != 0.f) send[e+0] = n;
    if (vo.y != 0.f) send[e+1] = n;
    if (vo.z != 0.f) send[e+2] = n;
    if (vo.w != 0.f) send[e+3] = n;
}

// ---------------- edge circuit: n=8, one wave/edge, 4 amps/lane ----------------
// lane masks: w0=32 w1=16 w3=8 w4=4 w6=2 w7=1; regs: w2=J1 w5=J0.
// Measure wire5 = J0. (math verified r2-r9; trig table-fed)
template<bool SCATTER>
__device__ __forceinline__ void edge_phase(
        int e, int lane,
        const float* __restrict__ H, const float* __restrict__ htrig,
        const int* __restrict__ send, const int* __restrict__ recv,
        const float* __restrict__ trig,
        float* __restrict__ out, float* __restrict__ macc) {
    int si = send[e], ri = recv[e];
    float4 t0 = ((const float4*)htrig)[si*2+0];
    float4 t1 = ((const float4*)htrig)[si*2+1];
    float4 t2 = ((const float4*)htrig)[ri*2+0];
    float4 t3 = ((const float4*)htrig)[ri*2+1];
    float ec[8] = {t0.x, t0.z, t1.x, t1.z, t2.x, t2.z, t3.x, t3.z};
    float es[8] = {t0.y, t0.w, t1.y, t1.w, t2.y, t2.w, t3.y, t3.w};

    float lp;
    {
        float f0 = (lane&32) ? es[0] : ec[0];
        float f1 = (lane&16) ? es[1] : ec[1];
        float f3 = (lane& 8) ? es[3] : ec[3];
        float f4 = (lane& 4) ? es[4] : ec[4];
        float f6 = (lane& 2) ? es[6] : ec[6];
        float f7 = (lane& 1) ? es[7] : ec[7];
        lp = f0*f1*f3*f4*f6*f7;
    }
    float a[4];
    a[0] = lp;
    a[1] = a[0]*es[5]; a[0] *= ec[5];          // J0 = wire5
    a[2] = a[0]*es[2]; a[3] = a[1]*es[2];      // J1 = wire2
    a[0] *= ec[2];     a[1] *= ec[2];

    const float* tc = trig;        // cos(te/2)
    const float* ts = trig + 16;   // sin(te/2)

    ry_l<4,32>(a, tc[0], ts[0], lane);         // th0 w0
    ry_l<4,16>(a, tc[1], ts[1], lane);         // th1 w1
    cx_ll<4,32,16>(a, lane);                   // cx 0,1
    ry_j<4,1>(a, tc[2], ts[2]);                // th2 w2
    ry_l<4,8>(a, tc[3], ts[3], lane);          // th3 w3 (DPP)
    cx_lj<4,8,1>(a, lane);                     // cx 3,2
    ry_l<4,4>(a, tc[4], ts[4], lane);          // th4 w4
    ry_j<4,0>(a, tc[5], ts[5]);                // th5 w5
    cx_lj<4,4,0>(a, lane);                     // cx 4,5
    ry_l<4,2>(a, tc[6], ts[6], lane);          // th6 w6 (DPP)
    ry_l<4,1>(a, tc[7], ts[7], lane);          // th7 w7 (DPP)
    cx_ll<4,1,2>(a, lane);                     // cx 7,6 (DPP tgt)
    ry_l<4,16>(a, tc[8], ts[8], lane);         // th8 w1
    ry_j<4,1>(a, tc[9], ts[9]);                // th9 w2
    cx_lj<4,16,1>(a, lane);                    // cx 1,2
    ry_j<4,0>(a, tc[10], ts[10]);              // th10 w5
    ry_l<4,2>(a, tc[11], ts[11], lane);        // th11 w6 (DPP)
    cx_lj<4,2,0>(a, lane);                     // cx 6,5
    ry_j<4,1>(a, tc[12], ts[12]);              // th12 w2
    ry_j<4,0>(a, tc[13], ts[13]);              // th13 w5
    cx_jj<4,1,0>(a);                           // cx 2,5
    ry_j<4,0>(a, tc[14], ts[14]);              // th14 w5

    float p = (a[0]*a[0] + a[2]*a[2]) - (a[1]*a[1] + a[3]*a[3]);
    p = wave_sum(p);
    float ev = (1.0f - p) * 0.5f;

    if (SCATTER) {
        if (lane < 8) {
            float4 hs = ((const float4*)H)[si];
            float4 hr = ((const float4*)H)[ri];
            float B[8] = {hs.x, hs.y, hs.z, hs.w, hr.x, hr.y, hr.z, hr.w};
            float bv = B[0];
            if (lane == 1) bv = B[1]; if (lane == 2) bv = B[2]; if (lane == 3) bv = B[3];
            if (lane == 4) bv = B[4]; if (lane == 5) bv = B[5]; if (lane == 6) bv = B[6];
            if (lane == 7) bv = B[7];
            int idx = (lane < 4) ? (ri*8 + lane) : (si*8 + 4 + (lane & 3));
            atomicAdd(&macc[idx], ev * bv);
        }
    } else {
        if (lane == 0) out[e] = ev;
    }
}

// ---------------- node circuit: n=12, TWO waves/node, 32 amps/lane ----------------
// (verified r7-r9) Amp index = W(1) | lane(6) | j(5).
// W = w11 (parity). Lane masks: w0=32 w1=16 w3=8 w4=4 w7=2 w8=1.
// Regs: J4=w2 J3=w5 J2=w6 J1=w9 J0=w10. Measure wire9 = J1 (bit 1 of j).
// W-dependence is a scalar factor until th11; cx(11,10) is parity-local.
// Lightcone: final 'ry th22 w4' acts after every gate touching w9's cone on a
// disjoint wire -> U†Z9U = Z9 -> dropped.
__device__ __forceinline__ void node_phase(
        int n, int par, int pair, int lane,
        const float* __restrict__ macc, float* __restrict__ H,
        float* __restrict__ htrig, const float* __restrict__ trig,
        float part[8][2]) {
    float4 m0 = ((const float4*)macc)[n*2];
    float4 m1 = ((const float4*)macc)[n*2+1];
    float M[8] = {m0.x, m0.y, m0.z, m0.w, m1.x, m1.y, m1.z, m1.w};

    float mc[12], ms[12];
#pragma unroll
    for (int k = 0; k < 8; ++k) __sincosf(0.5f * M[k], &ms[k], &mc[k]);
    {   // wires 8..11 angles are H[n][0..3]: trig precomputed
        float4 t0 = ((const float4*)htrig)[n*2+0];
        float4 t1 = ((const float4*)htrig)[n*2+1];
        mc[8] = t0.x; ms[8] = t0.y; mc[9]  = t0.z; ms[9]  = t0.w;
        mc[10]= t1.x; ms[10]= t1.y; mc[11] = t1.z; ms[11] = t1.w;
    }

    float lp;
    {
        float f0 = (lane&32) ? ms[0] : mc[0];
        float f1 = (lane&16) ? ms[1] : mc[1];
        float f3 = (lane& 8) ? ms[3] : mc[3];
        float f4 = (lane& 4) ? ms[4] : mc[4];
        float f7 = (lane& 2) ? ms[7] : mc[7];
        float f8 = (lane& 1) ? ms[8] : mc[8];
        lp = f0*f1*f3*f4*f7*f8;
    }
    float a[32];
    a[0] = lp;
    {   // doubling over J0=w10, J1=w9, J2=w6, J3=w5, J4=w2
        const int jw[5] = {10, 9, 6, 5, 2};
#pragma unroll
        for (int bnum = 0; bnum < 5; ++bnum) {
            int sz = 1 << bnum;
            float cw = mc[jw[bnum]], sw = ms[jw[bnum]];
#pragma unroll
            for (int k = 0; k < 32; ++k) {
                if (k < sz) {
                    a[k + sz] = a[k] * sw;
                    a[k] *= cw;
                }
            }
        }
    }

    const float* tc = trig + 32;   // cos(tn/2)
    const float* ts = trig + 56;   // sin(tn/2)

    ry_l<32,32>(a, tc[0], ts[0], lane);        // th0 w0
    ry_l<32,16>(a, tc[1], ts[1], lane);        // th1 w1
    cx_ll<32,32,16>(a, lane);                  // cx 0,1
    ry_j<32,4>(a, tc[2], ts[2]);               // th2 w2 (J4)
    ry_l<32,8>(a, tc[3], ts[3], lane);         // th3 w3 (DPP)
    cx_lj<32,8,4>(a, lane);                    // cx 3,2
    ry_l<32,4>(a, tc[4], ts[4], lane);         // th4 w4
    ry_j<32,3>(a, tc[5], ts[5]);               // th5 w5 (J3)
    cx_lj<32,4,3>(a, lane);                    // cx 4,5
    ry_j<32,2>(a, tc[6], ts[6]);               // th6 w6 (J2)
    ry_l<32,2>(a, tc[7], ts[7], lane);         // th7 w7 (DPP)
    cx_lj<32,2,2>(a, lane);                    // cx 7,6
    ry_l<32,1>(a, tc[8], ts[8], lane);         // th8 w8 (DPP)
    ry_j<32,1>(a, tc[9], ts[9]);               // th9 w9 (J1)
    cx_lj<32,1,1>(a, lane);                    // cx 8,9
    ry_j<32,0>(a, tc[10], ts[10]);             // th10 w10 (J0)
    {   // th11 w11 (W): scalar factor, rotated
        float f = par ? (ts[11]*mc[11] + tc[11]*ms[11])
                      : (tc[11]*mc[11] - ts[11]*ms[11]);
#pragma unroll
        for (int j = 0; j < 32; ++j) a[j] *= f;
    }
    if (par) {   // cx 11,10: parity-1 wave swaps J0 pairs
#pragma unroll
        for (int j = 0; j < 32; j += 2) {
            float t = a[j]; a[j] = a[j+1]; a[j+1] = t;
        }
    }
    ry_l<32,16>(a, tc[12], ts[12], lane);      // th12 w1
    ry_j<32,4>(a, tc[13], ts[13]);             // th13 w2
    cx_lj<32,16,4>(a, lane);                   // cx 1,2
    ry_j<32,3>(a, tc[14], ts[14]);             // th14 w5
    ry_j<32,2>(a, tc[15], ts[15]);             // th15 w6
    cx_jj<32,2,3>(a);                          // cx 6,5
    ry_j<32,1>(a, tc[16], ts[16]);             // th16 w9
    ry_j<32,0>(a, tc[17], ts[17]);             // th17 w10
    cx_jj<32,0,1>(a);                          // cx 10,9
    ry_j<32,4>(a, tc[18], ts[18]);             // th18 w2
    ry_j<32,3>(a, tc[19], ts[19]);             // th19 w5
    cx_jj<32,4,3>(a);                          // cx 2,5
    ry_j<32,3>(a, tc[20], ts[20]);             // th20 w5
    ry_j<32,1>(a, tc[21], ts[21]);             // th21 w9
    cx_jj<32,3,1>(a);                          // cx 5,9
    // th22 w4: dropped (outside measurement lightcone of wire 9)

    // <Z> on wire9 = J1 (bit 1 of j)
    float p = 0.f;
#pragma unroll
    for (int j = 0; j < 32; ++j) {
        float q = a[j]*a[j];
        p += (j & 2) ? -q : q;
    }
    p = wave_sum(p);
    if (lane == 0) part[pair][par] = p;
    __syncthreads();
    if (lane == 0 && par == 0) {
        float h = PI_F * (1.0f - (part[pair][0] + part[pair][1]));
        H[n*4+0] = h;
        float sh, ch;
        __sincosf(0.5f * h, &sh, &ch);
        htrig[n*8+0] = ch;       // keep htrig consistent for the next edge pass
        htrig[n*8+1] = sh;
    }
}

// ---------------- persistent mega-kernel: 5 phases, 4 grid barriers ----------
// 256 blocks x 1024 thr = 16 waves/block = 1 block/CU (VGPR forced <=128 by
// the 1024-thread block, node phase needs ~100 -> no spill). Replaces 5
// dependent kernel launches (edge0,node0,edge1,node1,edge2) with 1 dispatch.
__global__ __launch_bounds__(1024, 4) void k_mega(
        float* __restrict__ H, float* __restrict__ htrig,
        const int* __restrict__ send, const int* __restrict__ recv,
        const float* __restrict__ trig,
        float* __restrict__ maccA, float* __restrict__ maccB,
        float* __restrict__ out, int* __restrict__ bar) {
    __shared__ float part[8][2];
    int w    = threadIdx.x >> 6;        // wave in block: 0..15
    int lane = threadIdx.x & 63;
    int e    = blockIdx.x * 16 + w;     // edge id (4096 total)
    int n    = blockIdx.x * 8 + (w >> 1);   // node id (2048 total)
    int par  = w & 1;                   // W parity
    int pair = w >> 1;                  // node slot in block: 0..7

    // it 0
    edge_phase<true >(e, lane, H, htrig, send, recv, trig, nullptr, maccA);
    gridbar(&bar[0]);
    node_phase(n, par, pair, lane, maccA, H, htrig, trig, part);
    gridbar(&bar[1]);
    // it 1
    edge_phase<true >(e, lane, H, htrig, send, recv, trig, nullptr, maccB);
    gridbar(&bar[2]);
    node_phase(n, par, pair, lane, maccB, H, htrig, trig, part);
    gridbar(&bar[3]);
    // final edge -> out
    edge_phase<false>(e, lane, H, htrig, send, recv, trig, out, nullptr);
}

extern "C" void kernel_launch(void* const* d_in, const int* in_sizes, int n_in,
                              void* d_out, int out_size, void* d_ws, size_t ws_size,
                              hipStream_t stream) {
    const float* X  = (const float*)d_in[0];
    const float* Ri = (const float*)d_in[1];
    const float* Ro = (const float*)d_in[2];
    const float* W  = (const float*)d_in[3];
    const float* b  = (const float*)d_in[4];
    const float* te = (const float*)d_in[5];
    const float* tn = (const float*)d_in[6];
    float* out = (float*)d_out;

    int*   send  = (int*)d_ws;
    int*   recv  = send + N_EDGES;
    float* H     = (float*)(recv + N_EDGES);
    float* htrig = H + N_NODES * 4;
    float* maccA = htrig + N_NODES * 8;
    float* maccB = maccA + N_NODES * 8;
    float* trig  = maccB + N_NODES * 8;
    int*   bar   = (int*)(trig + 128);

    int total4 = (N_NODES * N_EDGES) / 4;          // one float4-pair per thread
    k_setup<<<total4 / 256, 256, 0, stream>>>(X, Ri, Ro, W, b, te, tn,
                                              send, recv, H, htrig,
                                              maccA, maccB, trig, bar);
    k_mega<<<NBLK, 1024, 0, stream>>>(H, htrig, send, recv, trig,
                                      maccA, maccB, out, bar);
}

// Round 2
// 163.217 us; speedup vs baseline: 1.2191x; 1.2191x over previous
//
#include <hip/hip_runtime.h>
#include <math.h>

#define N_NODES 2048
#define N_EDGES 4096
#define NBLK 256            // mega-kernel grid: 1 block/CU, co-resident by construction
#define PI_F 3.14159265358979323846f
#define TWO_PI_F 6.28318530717958647692f

// xor-shuffle with DPP fast paths (VALU, no DS pipe):
//   mask 1 -> quad_perm [1,0,3,2] (0xB1)
//   mask 2 -> quad_perm [2,3,0,1] (0x4E)
//   mask 8 -> row_ror:8 (0x128): (lane+8)%16 == lane^8 within each 16-row
// masks 4,16,32 stay on ds_bpermute via __shfl_xor.
template<int M>
__device__ __forceinline__ float shflx(float v) {
    if constexpr (M == 1) {
        return __int_as_float(__builtin_amdgcn_mov_dpp(
            __float_as_int(v), 0xB1, 0xF, 0xF, false));
    } else if constexpr (M == 2) {
        return __int_as_float(__builtin_amdgcn_mov_dpp(
            __float_as_int(v), 0x4E, 0xF, 0xF, false));
    } else if constexpr (M == 8) {
        return __int_as_float(__builtin_amdgcn_mov_dpp(
            __float_as_int(v), 0x128, 0xF, 0xF, false));
    } else {
        return __shfl_xor(v, M, 64);
    }
}

__device__ __forceinline__ float wave_sum(float p) {
    p += shflx<32>(p); p += shflx<16>(p); p += shflx<8>(p);
    p += shflx<4>(p);  p += shflx<2>(p);  p += shflx<1>(p);
    return p;
}

// ---- device-coherent (cross-XCD) scalar access: bypass non-coherent L1/L2.
// Relaxed agent-scope atomics lower to global_load/store with sc0 sc1 on
// gfx940+ (coherence-point access). NO cache flushes anywhere.
__device__ __forceinline__ float agent_load(const float* p) {
    return __hip_atomic_load(p, __ATOMIC_RELAXED, __HIP_MEMORY_SCOPE_AGENT);
}
__device__ __forceinline__ void agent_store(float* p, float v) {
    __hip_atomic_store(p, v, __ATOMIC_RELAXED, __HIP_MEMORY_SCOPE_AGENT);
}

// ---------------- gate helpers ----------------
// Amplitude index = lane*NA + j. j bits = in-register, lane bits above.
// RY pair semantics: new0 = c*s0 - s*s1 ; new1 = s*s0 + c*s1.

template<int NA, int B>
__device__ __forceinline__ void ry_j(float* a, float c, float s) {
#pragma unroll
    for (int j = 0; j < NA; ++j) {
        if ((j & (1 << B)) == 0) {
            int k = j | (1 << B);
            float x0 = a[j], x1 = a[k];
            a[j] = c * x0 - s * x1;
            a[k] = s * x0 + c * x1;
        }
    }
}

// MASK = lane-bit mask of the wire
template<int NA, int MASK>
__device__ __forceinline__ void ry_l(float* a, float c, float s, int lane) {
    float ss = (lane & MASK) ? s : -s;
#pragma unroll
    for (int j = 0; j < NA; ++j) {
        float p = shflx<MASK>(a[j]);
        a[j] = c * a[j] + ss * p;
    }
}

template<int NA, int BC, int BT>
__device__ __forceinline__ void cx_jj(float* a) {   // pure register rename
#pragma unroll
    for (int j = 0; j < NA; ++j) {
        if ((j & (1 << BC)) && !(j & (1 << BT))) {
            int k = j | (1 << BT);
            float t = a[j]; a[j] = a[k]; a[k] = t;
        }
    }
}

template<int NA, int MC, int BT>
__device__ __forceinline__ void cx_lj(float* a, int lane) {   // cndmask only
    bool sel = (lane & MC) != 0;
#pragma unroll
    for (int j = 0; j < NA; ++j) {
        if ((j & (1 << BT)) == 0) {
            int k = j | (1 << BT);
            float t0 = a[j], t1 = a[k];
            a[j] = sel ? t1 : t0;
            a[k] = sel ? t0 : t1;
        }
    }
}

template<int NA, int MC, int MT>
__device__ __forceinline__ void cx_ll(float* a, int lane) {
    bool sel = (lane & MC) != 0;
#pragma unroll
    for (int j = 0; j < NA; ++j) {
        float p = shflx<MT>(a[j]);
        a[j] = sel ? p : a[j];
    }
}

// ---------------- fence-free device-scope grid barrier ----------------
// No __threadfence (that emits an L2 wb/inv per call = the r1 80us stall).
// Protocol: every thread drains its own VMEM queue (s_waitcnt vmcnt(0)) so
// all block stores/atomics are complete AT THE COHERENCE POINT, then
// __syncthreads, then one relaxed agent-scope add + backoff spin. All
// cross-block mutable data is accessed via agent loads/stores (L2-bypass),
// so no invalidate is needed on the acquire side.
__device__ __forceinline__ void gridbar(int* cell) {
    asm volatile("s_waitcnt vmcnt(0)" ::: "memory");
    __syncthreads();
    if (threadIdx.x == 0) {
        __hip_atomic_fetch_add(cell, 1, __ATOMIC_RELAXED,
                               __HIP_MEMORY_SCOPE_AGENT);
        while (__hip_atomic_load(cell, __ATOMIC_RELAXED,
                                 __HIP_MEMORY_SCOPE_AGENT) < NBLK)
            __builtin_amdgcn_s_sleep(8);   // ~512cy backoff: cut coherence-point contention
    }
    __syncthreads();
}

// ---------------- setup: H0 + htrig + indices + macc zero + theta trig ----
// One float4-pair per thread (2M threads): measured HBM-bound (r2/r7).
__global__ __launch_bounds__(256) void k_setup(
        const float* __restrict__ X, const float* __restrict__ Ri,
        const float* __restrict__ Ro, const float* __restrict__ W,
        const float* __restrict__ b, const float* __restrict__ te,
        const float* __restrict__ tn,
        int* __restrict__ send, int* __restrict__ recv, float* __restrict__ H,
        float* __restrict__ htrig,
        float* __restrict__ maccA, float* __restrict__ maccB,
        float* __restrict__ trig, int* __restrict__ bar) {
    int tid = blockIdx.x * blockDim.x + threadIdx.x;
    if (tid < N_NODES) {
        float x0 = X[tid*3+0], x1 = X[tid*3+1], x2 = X[tid*3+2];
        float z = x0*W[0] + x1*W[1] + x2*W[2] + b[0];
        float sg = 1.0f / (1.0f + __expf(-z));
        float h = sg * TWO_PI_F;
        H[tid*4+0] = h;
        H[tid*4+1] = x0; H[tid*4+2] = x1; H[tid*4+3] = x2;
        float c0,s0,c1,s1,c2,s2,c3,s3;
        __sincosf(0.5f*h,  &s0, &c0);
        __sincosf(0.5f*x0, &s1, &c1);
        __sincosf(0.5f*x1, &s2, &c2);
        __sincosf(0.5f*x2, &s3, &c3);
        ((float4*)htrig)[tid*2+0] = make_float4(c0, s0, c1, s1);
        ((float4*)htrig)[tid*2+1] = make_float4(c2, s2, c3, s3);
    }
    if (tid < N_NODES * 8) { maccA[tid] = 0.f; maccB[tid] = 0.f; }
    if (tid < 4) bar[tid] = 0;                   // grid-barrier cells
    if (tid >= 4096 && tid < 4096 + 15) {        // edge theta trig
        int i = tid - 4096; float s, c;
        __sincosf(0.5f * te[i], &s, &c);
        trig[i] = c; trig[16 + i] = s;
    }
    if (tid >= 4224 && tid < 4224 + 23) {        // node theta trig
        int i = tid - 4224; float s, c;
        __sincosf(0.5f * tn[i], &s, &c);
        trig[32 + i] = c; trig[56 + i] = s;
    }
    const float4 vi = ((const float4*)Ri)[tid];
    const float4 vo = ((const float4*)Ro)[tid];
    int base = tid * 4;
    int n = base >> 12;             // row (E = 4096)
    int e = base & (N_EDGES - 1);   // col
    if (vi.x != 0.f) recv[e+0] = n;
    if (vi.y != 0.f) recv[e+1] = n;
    if (vi.z != 0.f) recv[e+2] = n;
    if (vi.w != 0.f) recv[e+3] = n;
    if (vo.x != 0.f) send[e+0] = n;
    if (vo.y != 0.f) send[e+1] = n;
    if (vo.z != 0.f) send[e+2] = n;
    if (vo.w != 0.f) send[e+3] = n;
}

// ---------------- edge circuit: n=8, one wave/edge, 4 amps/lane ----------------
// lane masks: w0=32 w1=16 w3=8 w4=4 w6=2 w7=1; regs: w2=J1 w5=J0.
// Measure wire5 = J0. (math verified r2-r9; trig table-fed)
// FRESH: htrig/H mutable components (h, ch, sh) were updated by a node phase
// since the last kernel boundary -> read them via agent loads (local L2 line
// may be stale in exactly those bytes; the rest of the line never changes).
template<bool SCATTER, bool FRESH>
__device__ __forceinline__ void edge_phase(
        int e, int lane,
        const float* __restrict__ H, const float* __restrict__ htrig,
        const int* __restrict__ send, const int* __restrict__ recv,
        const float* __restrict__ trig,
        float* __restrict__ out, float* __restrict__ macc) {
    int si = send[e], ri = recv[e];
    float4 t0 = ((const float4*)htrig)[si*2+0];
    float4 t1 = ((const float4*)htrig)[si*2+1];
    float4 t2 = ((const float4*)htrig)[ri*2+0];
    float4 t3 = ((const float4*)htrig)[ri*2+1];
    if (FRESH) {
        t0.x = agent_load(htrig + si*8 + 0);   // ch (mutable)
        t0.y = agent_load(htrig + si*8 + 1);   // sh (mutable)
        t2.x = agent_load(htrig + ri*8 + 0);
        t2.y = agent_load(htrig + ri*8 + 1);
    }
    float ec[8] = {t0.x, t0.z, t1.x, t1.z, t2.x, t2.z, t3.x, t3.z};
    float es[8] = {t0.y, t0.w, t1.y, t1.w, t2.y, t2.w, t3.y, t3.w};

    float lp;
    {
        float f0 = (lane&32) ? es[0] : ec[0];
        float f1 = (lane&16) ? es[1] : ec[1];
        float f3 = (lane& 8) ? es[3] : ec[3];
        float f4 = (lane& 4) ? es[4] : ec[4];
        float f6 = (lane& 2) ? es[6] : ec[6];
        float f7 = (lane& 1) ? es[7] : ec[7];
        lp = f0*f1*f3*f4*f6*f7;
    }
    float a[4];
    a[0] = lp;
    a[1] = a[0]*es[5]; a[0] *= ec[5];          // J0 = wire5
    a[2] = a[0]*es[2]; a[3] = a[1]*es[2];      // J1 = wire2
    a[0] *= ec[2];     a[1] *= ec[2];

    const float* tc = trig;        // cos(te/2)
    const float* ts = trig + 16;   // sin(te/2)

    ry_l<4,32>(a, tc[0], ts[0], lane);         // th0 w0
    ry_l<4,16>(a, tc[1], ts[1], lane);         // th1 w1
    cx_ll<4,32,16>(a, lane);                   // cx 0,1
    ry_j<4,1>(a, tc[2], ts[2]);                // th2 w2
    ry_l<4,8>(a, tc[3], ts[3], lane);          // th3 w3 (DPP)
    cx_lj<4,8,1>(a, lane);                     // cx 3,2
    ry_l<4,4>(a, tc[4], ts[4], lane);          // th4 w4
    ry_j<4,0>(a, tc[5], ts[5]);                // th5 w5
    cx_lj<4,4,0>(a, lane);                     // cx 4,5
    ry_l<4,2>(a, tc[6], ts[6], lane);          // th6 w6 (DPP)
    ry_l<4,1>(a, tc[7], ts[7], lane);          // th7 w7 (DPP)
    cx_ll<4,1,2>(a, lane);                     // cx 7,6 (DPP tgt)
    ry_l<4,16>(a, tc[8], ts[8], lane);         // th8 w1
    ry_j<4,1>(a, tc[9], ts[9]);                // th9 w2
    cx_lj<4,16,1>(a, lane);                    // cx 1,2
    ry_j<4,0>(a, tc[10], ts[10]);              // th10 w5
    ry_l<4,2>(a, tc[11], ts[11], lane);        // th11 w6 (DPP)
    cx_lj<4,2,0>(a, lane);                     // cx 6,5
    ry_j<4,1>(a, tc[12], ts[12]);              // th12 w2
    ry_j<4,0>(a, tc[13], ts[13]);              // th13 w5
    cx_jj<4,1,0>(a);                           // cx 2,5
    ry_j<4,0>(a, tc[14], ts[14]);              // th14 w5

    float p = (a[0]*a[0] + a[2]*a[2]) - (a[1]*a[1] + a[3]*a[3]);
    p = wave_sum(p);
    float ev = (1.0f - p) * 0.5f;

    if (SCATTER) {
        if (lane < 8) {
            float4 hs = ((const float4*)H)[si];
            float4 hr = ((const float4*)H)[ri];
            if (FRESH) {
                hs.x = agent_load(H + si*4);   // h (mutable)
                hr.x = agent_load(H + ri*4);
            }
            float B[8] = {hs.x, hs.y, hs.z, hs.w, hr.x, hr.y, hr.z, hr.w};
            float bv = B[0];
            if (lane == 1) bv = B[1]; if (lane == 2) bv = B[2]; if (lane == 3) bv = B[3];
            if (lane == 4) bv = B[4]; if (lane == 5) bv = B[5]; if (lane == 6) bv = B[6];
            if (lane == 7) bv = B[7];
            int idx = (lane < 4) ? (ri*8 + lane) : (si*8 + 4 + (lane & 3));
            atomicAdd(&macc[idx], ev * bv);    // device-scope: performed at coherence point
        }
    } else {
        if (lane == 0) out[e] = ev;
    }
}

// ---------------- node circuit: n=12, TWO waves/node, 32 amps/lane ----------------
// (verified r7-r9) Amp index = W(1) | lane(6) | j(5).
// W = w11 (parity). Lane masks: w0=32 w1=16 w3=8 w4=4 w7=2 w8=1.
// Regs: J4=w2 J3=w5 J2=w6 J1=w9 J0=w10. Measure wire9 = J1 (bit 1 of j).
// W-dependence is a scalar factor until th11; cx(11,10) is parity-local.
// Lightcone: final 'ry th22 w4' acts after every gate touching w9's cone on a
// disjoint wire -> U†Z9U = Z9 -> dropped.
// macc is always agent-loaded (edge atomics live at the coherence point).
// FRESH: htrig[n*8+0,1] were agent-stored by a previous node phase -> the
// locally cached line is stale in those bytes -> agent-load them.
template<bool FRESH>
__device__ __forceinline__ void node_phase(
        int n, int par, int pair, int lane,
        const float* __restrict__ macc, float* __restrict__ H,
        float* __restrict__ htrig, const float* __restrict__ trig,
        float part[8][2]) {
    float M[8];
#pragma unroll
    for (int k = 0; k < 8; ++k) M[k] = agent_load(macc + n*8 + k);

    float mc[12], ms[12];
#pragma unroll
    for (int k = 0; k < 8; ++k) __sincosf(0.5f * M[k], &ms[k], &mc[k]);
    {   // wires 8..11 angles are H[n][0..3]: trig precomputed
        float4 t0 = ((const float4*)htrig)[n*2+0];
        float4 t1 = ((const float4*)htrig)[n*2+1];
        if (FRESH) {
            t0.x = agent_load(htrig + n*8 + 0);
            t0.y = agent_load(htrig + n*8 + 1);
        }
        mc[8] = t0.x; ms[8] = t0.y; mc[9]  = t0.z; ms[9]  = t0.w;
        mc[10]= t1.x; ms[10]= t1.y; mc[11] = t1.z; ms[11] = t1.w;
    }

    float lp;
    {
        float f0 = (lane&32) ? ms[0] : mc[0];
        float f1 = (lane&16) ? ms[1] : mc[1];
        float f3 = (lane& 8) ? ms[3] : mc[3];
        float f4 = (lane& 4) ? ms[4] : mc[4];
        float f7 = (lane& 2) ? ms[7] : mc[7];
        float f8 = (lane& 1) ? ms[8] : mc[8];
        lp = f0*f1*f3*f4*f7*f8;
    }
    float a[32];
    a[0] = lp;
    {   // doubling over J0=w10, J1=w9, J2=w6, J3=w5, J4=w2
        const int jw[5] = {10, 9, 6, 5, 2};
#pragma unroll
        for (int bnum = 0; bnum < 5; ++bnum) {
            int sz = 1 << bnum;
            float cw = mc[jw[bnum]], sw = ms[jw[bnum]];
#pragma unroll
            for (int k = 0; k < 32; ++k) {
                if (k < sz) {
                    a[k + sz] = a[k] * sw;
                    a[k] *= cw;
                }
            }
        }
    }

    const float* tc = trig + 32;   // cos(tn/2)
    const float* ts = trig + 56;   // sin(tn/2)

    ry_l<32,32>(a, tc[0], ts[0], lane);        // th0 w0
    ry_l<32,16>(a, tc[1], ts[1], lane);        // th1 w1
    cx_ll<32,32,16>(a, lane);                  // cx 0,1
    ry_j<32,4>(a, tc[2], ts[2]);               // th2 w2 (J4)
    ry_l<32,8>(a, tc[3], ts[3], lane);         // th3 w3 (DPP)
    cx_lj<32,8,4>(a, lane);                    // cx 3,2
    ry_l<32,4>(a, tc[4], ts[4], lane);         // th4 w4
    ry_j<32,3>(a, tc[5], ts[5]);               // th5 w5 (J3)
    cx_lj<32,4,3>(a, lane);                    // cx 4,5
    ry_j<32,2>(a, tc[6], ts[6]);               // th6 w6 (J2)
    ry_l<32,2>(a, tc[7], ts[7], lane);         // th7 w7 (DPP)
    cx_lj<32,2,2>(a, lane);                    // cx 7,6
    ry_l<32,1>(a, tc[8], ts[8], lane);         // th8 w8 (DPP)
    ry_j<32,1>(a, tc[9], ts[9]);               // th9 w9 (J1)
    cx_lj<32,1,1>(a, lane);                    // cx 8,9
    ry_j<32,0>(a, tc[10], ts[10]);             // th10 w10 (J0)
    {   // th11 w11 (W): scalar factor, rotated
        float f = par ? (ts[11]*mc[11] + tc[11]*ms[11])
                      : (tc[11]*mc[11] - ts[11]*ms[11]);
#pragma unroll
        for (int j = 0; j < 32; ++j) a[j] *= f;
    }
    if (par) {   // cx 11,10: parity-1 wave swaps J0 pairs
#pragma unroll
        for (int j = 0; j < 32; j += 2) {
            float t = a[j]; a[j] = a[j+1]; a[j+1] = t;
        }
    }
    ry_l<32,16>(a, tc[12], ts[12], lane);      // th12 w1
    ry_j<32,4>(a, tc[13], ts[13]);             // th13 w2
    cx_lj<32,16,4>(a, lane);                   // cx 1,2
    ry_j<32,3>(a, tc[14], ts[14]);             // th14 w5
    ry_j<32,2>(a, tc[15], ts[15]);             // th15 w6
    cx_jj<32,2,3>(a);                          // cx 6,5
    ry_j<32,1>(a, tc[16], ts[16]);             // th16 w9
    ry_j<32,0>(a, tc[17], ts[17]);             // th17 w10
    cx_jj<32,0,1>(a);                          // cx 10,9
    ry_j<32,4>(a, tc[18], ts[18]);             // th18 w2
    ry_j<32,3>(a, tc[19], ts[19]);             // th19 w5
    cx_jj<32,4,3>(a);                          // cx 2,5
    ry_j<32,3>(a, tc[20], ts[20]);             // th20 w5
    ry_j<32,1>(a, tc[21], ts[21]);             // th21 w9
    cx_jj<32,3,1>(a);                          // cx 5,9
    // th22 w4: dropped (outside measurement lightcone of wire 9)

    // <Z> on wire9 = J1 (bit 1 of j)
    float p = 0.f;
#pragma unroll
    for (int j = 0; j < 32; ++j) {
        float q = a[j]*a[j];
        p += (j & 2) ? -q : q;
    }
    p = wave_sum(p);
    if (lane == 0) part[pair][par] = p;
    __syncthreads();
    if (lane == 0 && par == 0) {
        float h = PI_F * (1.0f - (part[pair][0] + part[pair][1]));
        float sh, ch;
        __sincosf(0.5f * h, &sh, &ch);
        // cross-block consumers (next edge phase) read these agent-scope:
        agent_store(H + n*4 + 0, h);
        agent_store(htrig + n*8 + 0, ch);
        agent_store(htrig + n*8 + 1, sh);
    }
}

// ---------------- persistent mega-kernel: 5 phases, 4 fence-free barriers ----
// 256 blocks x 1024 thr = 16 waves/block = 1 block/CU. VGPR=56 (r1 measured,
// no spill). Replaces 5 dependent kernel launches with 1 dispatch.
__global__ __launch_bounds__(1024, 4) void k_mega(
        float* __restrict__ H, float* __restrict__ htrig,
        const int* __restrict__ send, const int* __restrict__ recv,
        const float* __restrict__ trig,
        float* __restrict__ maccA, float* __restrict__ maccB,
        float* __restrict__ out, int* __restrict__ bar) {
    __shared__ float part[8][2];
    int w    = threadIdx.x >> 6;        // wave in block: 0..15
    int lane = threadIdx.x & 63;
    int e    = blockIdx.x * 16 + w;     // edge id (4096 total)
    int n    = blockIdx.x * 8 + (w >> 1);   // node id (2048 total)
    int par  = w & 1;                   // W parity
    int pair = w >> 1;                  // node slot in block: 0..7

    // it 0 (all inputs from k_setup: plain loads fine via launch boundary)
    edge_phase<true, false>(e, lane, H, htrig, send, recv, trig, nullptr, maccA);
    gridbar(&bar[0]);
    node_phase<false>(n, par, pair, lane, maccA, H, htrig, trig, part);
    gridbar(&bar[1]);
    // it 1 (h/ch/sh now agent-written -> FRESH reads)
    edge_phase<true, true >(e, lane, H, htrig, send, recv, trig, nullptr, maccB);
    gridbar(&bar[2]);
    node_phase<true >(n, par, pair, lane, maccB, H, htrig, trig, part);
    gridbar(&bar[3]);
    // final edge -> out
    edge_phase<false, true>(e, lane, H, htrig, send, recv, trig, out, nullptr);
}

extern "C" void kernel_launch(void* const* d_in, const int* in_sizes, int n_in,
                              void* d_out, int out_size, void* d_ws, size_t ws_size,
                              hipStream_t stream) {
    const float* X  = (const float*)d_in[0];
    const float* Ri = (const float*)d_in[1];
    const float* Ro = (const float*)d_in[2];
    const float* W  = (const float*)d_in[3];
    const float* b  = (const float*)d_in[4];
    const float* te = (const float*)d_in[5];
    const float* tn = (const float*)d_in[6];
    float* out = (float*)d_out;

    int*   send  = (int*)d_ws;
    int*   recv  = send + N_EDGES;
    float* H     = (float*)(recv + N_EDGES);
    float* htrig = H + N_NODES * 4;
    float* maccA = htrig + N_NODES * 8;
    float* maccB = maccA + N_NODES * 8;
    float* trig  = maccB + N_NODES * 8;
    int*   bar   = (int*)(trig + 128);

    int total4 = (N_NODES * N_EDGES) / 4;          // one float4-pair per thread
    k_setup<<<total4 / 256, 256, 0, stream>>>(X, Ri, Ro, W, b, te, tn,
                                              send, recv, H, htrig,
                                              maccA, maccB, trig, bar);
    k_mega<<<NBLK, 1024, 0, stream>>>(H, htrig, send, recv, trig,
                                      maccA, maccB, out, bar);
}

// Round 3
// 155.578 us; speedup vs baseline: 1.2789x; 1.0491x over previous
//
#include <hip/hip_runtime.h>
#include <math.h>

#define N_NODES 2048
#define N_EDGES 4096
#define NBLK 256            // mega-kernel grid: 1 block/CU, co-resident by construction
#define PI_F 3.14159265358979323846f
#define TWO_PI_F 6.28318530717958647692f

// xor-shuffle with DPP fast paths (VALU, no DS pipe):
//   mask 1 -> quad_perm [1,0,3,2] (0xB1)
//   mask 2 -> quad_perm [2,3,0,1] (0x4E)
//   mask 8 -> row_ror:8 (0x128): (lane+8)%16 == lane^8 within each 16-row
// masks 4,16,32 stay on ds_bpermute via __shfl_xor.
template<int M>
__device__ __forceinline__ float shflx(float v) {
    if constexpr (M == 1) {
        return __int_as_float(__builtin_amdgcn_mov_dpp(
            __float_as_int(v), 0xB1, 0xF, 0xF, false));
    } else if constexpr (M == 2) {
        return __int_as_float(__builtin_amdgcn_mov_dpp(
            __float_as_int(v), 0x4E, 0xF, 0xF, false));
    } else if constexpr (M == 8) {
        return __int_as_float(__builtin_amdgcn_mov_dpp(
            __float_as_int(v), 0x128, 0xF, 0xF, false));
    } else {
        return __shfl_xor(v, M, 64);
    }
}

__device__ __forceinline__ float wave_sum(float p) {
    p += shflx<32>(p); p += shflx<16>(p); p += shflx<8>(p);
    p += shflx<4>(p);  p += shflx<2>(p);  p += shflx<1>(p);
    return p;
}

// ---- device-coherent (cross-XCD) scalar access: bypass non-coherent L1/L2.
__device__ __forceinline__ float agent_load(const float* p) {
    return __hip_atomic_load(p, __ATOMIC_RELAXED, __HIP_MEMORY_SCOPE_AGENT);
}
__device__ __forceinline__ void agent_store(float* p, float v) {
    __hip_atomic_store(p, v, __ATOMIC_RELAXED, __HIP_MEMORY_SCOPE_AGENT);
}
__device__ __forceinline__ void agent_store_i(int* p, int v) {
    __hip_atomic_store(p, v, __ATOMIC_RELAXED, __HIP_MEMORY_SCOPE_AGENT);
}
// spin until *p >= v. Wave-uniform address: 64 lanes coalesce to one request.
// Distributed cells (per-node), so no hot-line contention. Compiler fence at
// exit keeps dependent agent loads from being hoisted above the spin.
__device__ __forceinline__ void spin_ge(const int* p, int v) {
    while (__hip_atomic_load(p, __ATOMIC_RELAXED, __HIP_MEMORY_SCOPE_AGENT) < v)
        __builtin_amdgcn_s_sleep(4);
    asm volatile("" ::: "memory");
}

// ---------------- gate helpers ----------------
// Amplitude index = lane*NA + j. j bits = in-register, lane bits above.
// RY pair semantics: new0 = c*s0 - s*s1 ; new1 = s*s0 + c*s1.

template<int NA, int B>
__device__ __forceinline__ void ry_j(float* a, float c, float s) {
#pragma unroll
    for (int j = 0; j < NA; ++j) {
        if ((j & (1 << B)) == 0) {
            int k = j | (1 << B);
            float x0 = a[j], x1 = a[k];
            a[j] = c * x0 - s * x1;
            a[k] = s * x0 + c * x1;
        }
    }
}

// MASK = lane-bit mask of the wire
template<int NA, int MASK>
__device__ __forceinline__ void ry_l(float* a, float c, float s, int lane) {
    float ss = (lane & MASK) ? s : -s;
#pragma unroll
    for (int j = 0; j < NA; ++j) {
        float p = shflx<MASK>(a[j]);
        a[j] = c * a[j] + ss * p;
    }
}

template<int NA, int BC, int BT>
__device__ __forceinline__ void cx_jj(float* a) {   // pure register rename
#pragma unroll
    for (int j = 0; j < NA; ++j) {
        if ((j & (1 << BC)) && !(j & (1 << BT))) {
            int k = j | (1 << BT);
            float t = a[j]; a[j] = a[k]; a[k] = t;
        }
    }
}

template<int NA, int MC, int BT>
__device__ __forceinline__ void cx_lj(float* a, int lane) {   // cndmask only
    bool sel = (lane & MC) != 0;
#pragma unroll
    for (int j = 0; j < NA; ++j) {
        if ((j & (1 << BT)) == 0) {
            int k = j | (1 << BT);
            float t0 = a[j], t1 = a[k];
            a[j] = sel ? t1 : t0;
            a[k] = sel ? t0 : t1;
        }
    }
}

template<int NA, int MC, int MT>
__device__ __forceinline__ void cx_ll(float* a, int lane) {
    bool sel = (lane & MC) != 0;
#pragma unroll
    for (int j = 0; j < NA; ++j) {
        float p = shflx<MT>(a[j]);
        a[j] = sel ? p : a[j];
    }
}

// ---------------- setup: H0 + htrig + indices + deg + theta trig ----------
// One float4-pair per thread (2M threads): measured HBM-bound (r2/r7).
// macc/arr/epoch/deg zeroed by a preceding hipMemsetAsync (stream-ordered),
// so the deg atomics here don't race the zeroing.
__global__ __launch_bounds__(256) void k_setup(
        const float* __restrict__ X, const float* __restrict__ Ri,
        const float* __restrict__ Ro, const float* __restrict__ W,
        const float* __restrict__ b, const float* __restrict__ te,
        const float* __restrict__ tn,
        int* __restrict__ send, int* __restrict__ recv, float* __restrict__ H,
        float* __restrict__ htrig, float* __restrict__ trig,
        int* __restrict__ deg) {
    int tid = blockIdx.x * blockDim.x + threadIdx.x;
    if (tid < N_NODES) {
        float x0 = X[tid*3+0], x1 = X[tid*3+1], x2 = X[tid*3+2];
        float z = x0*W[0] + x1*W[1] + x2*W[2] + b[0];
        float sg = 1.0f / (1.0f + __expf(-z));
        float h = sg * TWO_PI_F;
        H[tid*4+0] = h;
        H[tid*4+1] = x0; H[tid*4+2] = x1; H[tid*4+3] = x2;
        float c0,s0,c1,s1,c2,s2,c3,s3;
        __sincosf(0.5f*h,  &s0, &c0);
        __sincosf(0.5f*x0, &s1, &c1);
        __sincosf(0.5f*x1, &s2, &c2);
        __sincosf(0.5f*x2, &s3, &c3);
        ((float4*)htrig)[tid*2+0] = make_float4(c0, s0, c1, s1);
        ((float4*)htrig)[tid*2+1] = make_float4(c2, s2, c3, s3);
    }
    if (tid >= 4096 && tid < 4096 + 15) {        // edge theta trig
        int i = tid - 4096; float s, c;
        __sincosf(0.5f * te[i], &s, &c);
        trig[i] = c; trig[16 + i] = s;
    }
    if (tid >= 4224 && tid < 4224 + 23) {        // node theta trig
        int i = tid - 4224; float s, c;
        __sincosf(0.5f * tn[i], &s, &c);
        trig[32 + i] = c; trig[56 + i] = s;
    }
    const float4 vi = ((const float4*)Ri)[tid];
    const float4 vo = ((const float4*)Ro)[tid];
    int base = tid * 4;
    int n = base >> 12;             // row (E = 4096)
    int e = base & (N_EDGES - 1);   // col
    int cnt = 0;
    if (vi.x != 0.f) { recv[e+0] = n; ++cnt; }
    if (vi.y != 0.f) { recv[e+1] = n; ++cnt; }
    if (vi.z != 0.f) { recv[e+2] = n; ++cnt; }
    if (vi.w != 0.f) { recv[e+3] = n; ++cnt; }
    if (vo.x != 0.f) { send[e+0] = n; ++cnt; }
    if (vo.y != 0.f) { send[e+1] = n; ++cnt; }
    if (vo.z != 0.f) { send[e+2] = n; ++cnt; }
    if (vo.w != 0.f) { send[e+3] = n; ++cnt; }
    if (cnt) atomicAdd(&deg[n], cnt);   // deg[n] = indeg + outdeg
}

// ---------------- edge circuit: n=8, one wave/edge, 4 amps/lane ----------------
// lane masks: w0=32 w1=16 w3=8 w4=4 w6=2 w7=1; regs: w2=J1 w5=J0.
// Measure wire5 = J0. (math verified r2-r9; trig table-fed)
// IT>0: endpoints' h/ch/sh were produced by node waves of round IT -> spin on
// per-node epoch, then read the mutable scalars via agent loads.
// After scatter: drain vmcnt (macc atomics complete at coherence point), then
// publish arrival ticks so the consumer nodes can start.
template<int IT, bool SCATTER>
__device__ __forceinline__ void edge_phase(
        int e, int lane,
        const float* __restrict__ H, const float* __restrict__ htrig,
        const int* __restrict__ send, const int* __restrict__ recv,
        const float* __restrict__ trig,
        float* __restrict__ out, float* __restrict__ macc,
        int* __restrict__ arr, const int* __restrict__ epoch) {
    int si = send[e], ri = recv[e];
    if (IT > 0) {                       // wait for endpoint nodes of round IT
        spin_ge(epoch + si, IT);
        spin_ge(epoch + ri, IT);
    }
    float4 t0 = ((const float4*)htrig)[si*2+0];
    float4 t1 = ((const float4*)htrig)[si*2+1];
    float4 t2 = ((const float4*)htrig)[ri*2+0];
    float4 t3 = ((const float4*)htrig)[ri*2+1];
    if (IT > 0) {
        t0.x = agent_load(htrig + si*8 + 0);   // ch (mutable)
        t0.y = agent_load(htrig + si*8 + 1);   // sh (mutable)
        t2.x = agent_load(htrig + ri*8 + 0);
        t2.y = agent_load(htrig + ri*8 + 1);
    }
    float ec[8] = {t0.x, t0.z, t1.x, t1.z, t2.x, t2.z, t3.x, t3.z};
    float es[8] = {t0.y, t0.w, t1.y, t1.w, t2.y, t2.w, t3.y, t3.w};

    float lp;
    {
        float f0 = (lane&32) ? es[0] : ec[0];
        float f1 = (lane&16) ? es[1] : ec[1];
        float f3 = (lane& 8) ? es[3] : ec[3];
        float f4 = (lane& 4) ? es[4] : ec[4];
        float f6 = (lane& 2) ? es[6] : ec[6];
        float f7 = (lane& 1) ? es[7] : ec[7];
        lp = f0*f1*f3*f4*f6*f7;
    }
    float a[4];
    a[0] = lp;
    a[1] = a[0]*es[5]; a[0] *= ec[5];          // J0 = wire5
    a[2] = a[0]*es[2]; a[3] = a[1]*es[2];      // J1 = wire2
    a[0] *= ec[2];     a[1] *= ec[2];

    const float* tc = trig;        // cos(te/2)
    const float* ts = trig + 16;   // sin(te/2)

    ry_l<4,32>(a, tc[0], ts[0], lane);         // th0 w0
    ry_l<4,16>(a, tc[1], ts[1], lane);         // th1 w1
    cx_ll<4,32,16>(a, lane);                   // cx 0,1
    ry_j<4,1>(a, tc[2], ts[2]);                // th2 w2
    ry_l<4,8>(a, tc[3], ts[3], lane);          // th3 w3 (DPP)
    cx_lj<4,8,1>(a, lane);                     // cx 3,2
    ry_l<4,4>(a, tc[4], ts[4], lane);          // th4 w4
    ry_j<4,0>(a, tc[5], ts[5]);                // th5 w5
    cx_lj<4,4,0>(a, lane);                     // cx 4,5
    ry_l<4,2>(a, tc[6], ts[6], lane);          // th6 w6 (DPP)
    ry_l<4,1>(a, tc[7], ts[7], lane);          // th7 w7 (DPP)
    cx_ll<4,1,2>(a, lane);                     // cx 7,6 (DPP tgt)
    ry_l<4,16>(a, tc[8], ts[8], lane);         // th8 w1
    ry_j<4,1>(a, tc[9], ts[9]);                // th9 w2
    cx_lj<4,16,1>(a, lane);                    // cx 1,2
    ry_j<4,0>(a, tc[10], ts[10]);              // th10 w5
    ry_l<4,2>(a, tc[11], ts[11], lane);        // th11 w6 (DPP)
    cx_lj<4,2,0>(a, lane);                     // cx 6,5
    ry_j<4,1>(a, tc[12], ts[12]);              // th12 w2
    ry_j<4,0>(a, tc[13], ts[13]);              // th13 w5
    cx_jj<4,1,0>(a);                           // cx 2,5
    ry_j<4,0>(a, tc[14], ts[14]);              // th14 w5

    float p = (a[0]*a[0] + a[2]*a[2]) - (a[1]*a[1] + a[3]*a[3]);
    p = wave_sum(p);
    float ev = (1.0f - p) * 0.5f;

    if (SCATTER) {
        if (lane < 8) {
            float4 hs = ((const float4*)H)[si];
            float4 hr = ((const float4*)H)[ri];
            if (IT > 0) {
                hs.x = agent_load(H + si*4);   // h (mutable)
                hr.x = agent_load(H + ri*4);
            }
            float B[8] = {hs.x, hs.y, hs.z, hs.w, hr.x, hr.y, hr.z, hr.w};
            float bv = B[0];
            if (lane == 1) bv = B[1]; if (lane == 2) bv = B[2]; if (lane == 3) bv = B[3];
            if (lane == 4) bv = B[4]; if (lane == 5) bv = B[5]; if (lane == 6) bv = B[6];
            if (lane == 7) bv = B[7];
            int idx = (lane < 4) ? (ri*8 + lane) : (si*8 + 4 + (lane & 3));
            atomicAdd(&macc[idx], ev * bv);    // device-scope: lands at coherence point
        }
        // publish: all 8 lanes' atomics are in this wave's vmcnt queue.
        asm volatile("s_waitcnt vmcnt(0)" ::: "memory");
        if (lane == 0) {
            atomicAdd(&arr[ri], 1);
            atomicAdd(&arr[si], 1);
        }
    } else {
        if (lane == 0) out[e] = ev;
    }
}

// ---------------- node circuit: n=12, TWO waves/node, 32 amps/lane ----------------
// (verified r7-r9) Amp index = W(1) | lane(6) | j(5).
// W = w11 (parity). Lane masks: w0=32 w1=16 w3=8 w4=4 w7=2 w8=1.
// Regs: J4=w2 J3=w5 J2=w6 J1=w9 J0=w10. Measure wire9 = J1 (bit 1 of j).
// Waits on arr[n] == deg[n] (its own edges only -> starts as soon as THEY are
// done, no global barrier). Pair combine via LDS flag (ds ops, no block sync).
template<int IT>
__device__ __forceinline__ void node_phase(
        int n, int par, int pair, int lane,
        const float* __restrict__ macc, const int* __restrict__ arr,
        const int* __restrict__ deg,
        float* __restrict__ H, float* __restrict__ htrig,
        const float* __restrict__ trig,
        float* part1, int* pflag, int* __restrict__ epoch) {
    int d = deg[n];
    spin_ge(arr + n, d);                 // all my edges have scattered

    float M[8];
#pragma unroll
    for (int k = 0; k < 8; ++k) M[k] = agent_load(macc + n*8 + k);

    float mc[12], ms[12];
#pragma unroll
    for (int k = 0; k < 8; ++k) __sincosf(0.5f * M[k], &ms[k], &mc[k]);
    {   // wires 8..11 angles are H[n][0..3]: trig precomputed
        float4 t0 = ((const float4*)htrig)[n*2+0];
        float4 t1 = ((const float4*)htrig)[n*2+1];
        if (IT > 0) {
            t0.x = agent_load(htrig + n*8 + 0);
            t0.y = agent_load(htrig + n*8 + 1);
        }
        mc[8] = t0.x; ms[8] = t0.y; mc[9]  = t0.z; ms[9]  = t0.w;
        mc[10]= t1.x; ms[10]= t1.y; mc[11] = t1.z; ms[11] = t1.w;
    }

    float lp;
    {
        float f0 = (lane&32) ? ms[0] : mc[0];
        float f1 = (lane&16) ? ms[1] : mc[1];
        float f3 = (lane& 8) ? ms[3] : mc[3];
        float f4 = (lane& 4) ? ms[4] : mc[4];
        float f7 = (lane& 2) ? ms[7] : mc[7];
        float f8 = (lane& 1) ? ms[8] : mc[8];
        lp = f0*f1*f3*f4*f7*f8;
    }
    float a[32];
    a[0] = lp;
    {   // doubling over J0=w10, J1=w9, J2=w6, J3=w5, J4=w2
        const int jw[5] = {10, 9, 6, 5, 2};
#pragma unroll
        for (int bnum = 0; bnum < 5; ++bnum) {
            int sz = 1 << bnum;
            float cw = mc[jw[bnum]], sw = ms[jw[bnum]];
#pragma unroll
            for (int k = 0; k < 32; ++k) {
                if (k < sz) {
                    a[k + sz] = a[k] * sw;
                    a[k] *= cw;
                }
            }
        }
    }

    const float* tc = trig + 32;   // cos(tn/2)
    const float* ts = trig + 56;   // sin(tn/2)

    ry_l<32,32>(a, tc[0], ts[0], lane);        // th0 w0
    ry_l<32,16>(a, tc[1], ts[1], lane);        // th1 w1
    cx_ll<32,32,16>(a, lane);                  // cx 0,1
    ry_j<32,4>(a, tc[2], ts[2]);               // th2 w2 (J4)
    ry_l<32,8>(a, tc[3], ts[3], lane);         // th3 w3 (DPP)
    cx_lj<32,8,4>(a, lane);                    // cx 3,2
    ry_l<32,4>(a, tc[4], ts[4], lane);         // th4 w4
    ry_j<32,3>(a, tc[5], ts[5]);               // th5 w5 (J3)
    cx_lj<32,4,3>(a, lane);                    // cx 4,5
    ry_j<32,2>(a, tc[6], ts[6]);               // th6 w6 (J2)
    ry_l<32,2>(a, tc[7], ts[7], lane);         // th7 w7 (DPP)
    cx_lj<32,2,2>(a, lane);                    // cx 7,6
    ry_l<32,1>(a, tc[8], ts[8], lane);         // th8 w8 (DPP)
    ry_j<32,1>(a, tc[9], ts[9]);               // th9 w9 (J1)
    cx_lj<32,1,1>(a, lane);                    // cx 8,9
    ry_j<32,0>(a, tc[10], ts[10]);             // th10 w10 (J0)
    {   // th11 w11 (W): scalar factor, rotated
        float f = par ? (ts[11]*mc[11] + tc[11]*ms[11])
                      : (tc[11]*mc[11] - ts[11]*ms[11]);
#pragma unroll
        for (int j = 0; j < 32; ++j) a[j] *= f;
    }
    if (par) {   // cx 11,10: parity-1 wave swaps J0 pairs
#pragma unroll
        for (int j = 0; j < 32; j += 2) {
            float t = a[j]; a[j] = a[j+1]; a[j+1] = t;
        }
    }
    ry_l<32,16>(a, tc[12], ts[12], lane);      // th12 w1
    ry_j<32,4>(a, tc[13], ts[13]);             // th13 w2
    cx_lj<32,16,4>(a, lane);                   // cx 1,2
    ry_j<32,3>(a, tc[14], ts[14]);             // th14 w5
    ry_j<32,2>(a, tc[15], ts[15]);             // th15 w6
    cx_jj<32,2,3>(a);                          // cx 6,5
    ry_j<32,1>(a, tc[16], ts[16]);             // th16 w9
    ry_j<32,0>(a, tc[17], ts[17]);             // th17 w10
    cx_jj<32,0,1>(a);                          // cx 10,9
    ry_j<32,4>(a, tc[18], ts[18]);             // th18 w2
    ry_j<32,3>(a, tc[19], ts[19]);             // th19 w5
    cx_jj<32,4,3>(a);                          // cx 2,5
    ry_j<32,3>(a, tc[20], ts[20]);             // th20 w5
    ry_j<32,1>(a, tc[21], ts[21]);             // th21 w9
    cx_jj<32,3,1>(a);                          // cx 5,9
    // th22 w4: dropped (outside measurement lightcone of wire 9)

    // <Z> on wire9 = J1 (bit 1 of j)
    float p = 0.f;
#pragma unroll
    for (int j = 0; j < 32; ++j) {
        float q = a[j]*a[j];
        p += (j & 2) ? -q : q;
    }
    p = wave_sum(p);

    if (par == 1) {
        if (lane == 0) {
            part1[pair] = p;
            __hip_atomic_store(&pflag[pair], IT + 1, __ATOMIC_RELEASE,
                               __HIP_MEMORY_SCOPE_WORKGROUP);
        }
    } else {
        if (lane == 0) {
            while (__hip_atomic_load(&pflag[pair], __ATOMIC_ACQUIRE,
                                     __HIP_MEMORY_SCOPE_WORKGROUP) < IT + 1)
                __builtin_amdgcn_s_sleep(1);
            float h = PI_F * (1.0f - (p + part1[pair]));
            float sh, ch;
            __sincosf(0.5f * h, &sh, &ch);
            agent_store(H + n*4 + 0, h);
            agent_store(htrig + n*8 + 0, ch);
            agent_store(htrig + n*8 + 1, sh);
            asm volatile("s_waitcnt vmcnt(0)" ::: "memory");   // h/ch/sh visible...
            agent_store_i(epoch + n, IT + 1);                  // ...before the tick
        }
    }
}

// ---------------- persistent mega-kernel: pure dataflow, zero global barriers ----
// 256 blocks x 1024 thr. Wave w: edge e=b*16+w, node n=b*8+(w>>1), par=w&1.
// Sync: per-node arrival counters (edge->node) + per-node epochs (node->edge)
// + LDS flag for the intra-pair combine. All waits follow the DAG and all
// blocks are resident -> no deadlock, maximal phase overlap.
__global__ __launch_bounds__(1024, 4) void k_mega(
        float* __restrict__ H, float* __restrict__ htrig,
        const int* __restrict__ send, const int* __restrict__ recv,
        const float* __restrict__ trig,
        float* __restrict__ maccA, float* __restrict__ maccB,
        int* __restrict__ arrA, int* __restrict__ arrB,
        int* __restrict__ epoch, const int* __restrict__ deg,
        float* __restrict__ out) {
    __shared__ float part1[8];
    __shared__ int pflag[8];
    if (threadIdx.x < 8) pflag[threadIdx.x] = 0;
    __syncthreads();

    int w    = threadIdx.x >> 6;        // wave in block: 0..15
    int lane = threadIdx.x & 63;
    int e    = blockIdx.x * 16 + w;     // edge id (4096 total)
    int n    = blockIdx.x * 8 + (w >> 1);   // node id (2048 total)
    int par  = w & 1;                   // W parity
    int pair = w >> 1;                  // node slot in block: 0..7

    // it 0
    edge_phase<0, true >(e, lane, H, htrig, send, recv, trig, nullptr, maccA, arrA, epoch);
    node_phase<0>(n, par, pair, lane, maccA, arrA, deg, H, htrig, trig, part1, pflag, epoch);
    // it 1
    edge_phase<1, true >(e, lane, H, htrig, send, recv, trig, nullptr, maccB, arrB, epoch);
    node_phase<1>(n, par, pair, lane, maccB, arrB, deg, H, htrig, trig, part1, pflag, epoch);
    // final edge -> out
    edge_phase<2, false>(e, lane, H, htrig, send, recv, trig, out, nullptr, nullptr, epoch);
}

extern "C" void kernel_launch(void* const* d_in, const int* in_sizes, int n_in,
                              void* d_out, int out_size, void* d_ws, size_t ws_size,
                              hipStream_t stream) {
    const float* X  = (const float*)d_in[0];
    const float* Ri = (const float*)d_in[1];
    const float* Ro = (const float*)d_in[2];
    const float* W  = (const float*)d_in[3];
    const float* b  = (const float*)d_in[4];
    const float* te = (const float*)d_in[5];
    const float* tn = (const float*)d_in[6];
    float* out = (float*)d_out;

    int*   send  = (int*)d_ws;                      // [4096]
    int*   recv  = send + N_EDGES;                  // [4096]
    float* H     = (float*)(recv + N_EDGES);        // [8192]
    float* htrig = H + N_NODES * 4;                 // [16384] (16B-aligned)
    float* trig  = htrig + N_NODES * 8;             // [128]
    // ---- zero region (one memset, stream-ordered before k_setup) ----
    float* maccA = trig + 128;                      // [16384]
    float* maccB = maccA + N_NODES * 8;             // [16384]
    int*   arrA  = (int*)(maccB + N_NODES * 8);     // [2048]
    int*   arrB  = arrA + N_NODES;                  // [2048]
    int*   epoch = arrB + N_NODES;                  // [2048]
    int*   deg   = epoch + N_NODES;                 // [2048]
    size_t zbytes = (size_t)(2 * N_NODES * 8 + 4 * N_NODES) * sizeof(float);

    hipMemsetAsync((void*)maccA, 0, zbytes, stream);
    int total4 = (N_NODES * N_EDGES) / 4;           // one float4-pair per thread
    k_setup<<<total4 / 256, 256, 0, stream>>>(X, Ri, Ro, W, b, te, tn,
                                              send, recv, H, htrig, trig, deg);
    k_mega<<<NBLK, 1024, 0, stream>>>(H, htrig, send, recv, trig,
                                      maccA, maccB, arrA, arrB, epoch, deg, out);
}

// Round 4
// 123.459 us; speedup vs baseline: 1.6116x; 1.2602x over previous
//
#include <hip/hip_runtime.h>
#include <math.h>

#define N_NODES 2048
#define N_EDGES 4096
#define PI_F 3.14159265358979323846f
#define TWO_PI_F 6.28318530717958647692f

// ---- device-coherent (cross-XCD) scalar access: bypass non-coherent L1/L2.
__device__ __forceinline__ float agent_load(const float* p) {
    return __hip_atomic_load(p, __ATOMIC_RELAXED, __HIP_MEMORY_SCOPE_AGENT);
}
__device__ __forceinline__ void agent_store(float* p, float v) {
    __hip_atomic_store(p, v, __ATOMIC_RELAXED, __HIP_MEMORY_SCOPE_AGENT);
}
__device__ __forceinline__ void agent_store_i(int* p, int v) {
    __hip_atomic_store(p, v, __ATOMIC_RELAXED, __HIP_MEMORY_SCOPE_AGENT);
}
// spin until *p >= v (per-lane predicate; masked loop). Distributed cells.
__device__ __forceinline__ void spin_ge(const int* p, int v) {
    while (__hip_atomic_load(p, __ATOMIC_RELAXED, __HIP_MEMORY_SCOPE_AGENT) < v)
        __builtin_amdgcn_s_sleep(2);
    asm volatile("" ::: "memory");
}

// ================= 16-amplitude 4-wire sub-circuit =================
// Bit map: wire W0->bit8, W1->bit4, W2->bit2, W3->bit1.
// Gate template (both circuit families factorize to this; verified against
// EDGE_OPS/NODE_OPS gate-by-gate):
//   RY(t0,W0) RY(t1,W1) CX(W0,W1) RY(t2,W2) RY(t3,W3) CX(W3,W2)
//   RY(t4,W1) RY(t5,W2)
//   A-type: CX(W1,W2) RY(t6,W2)   -> returns <Z_W2>
//   B-type: CX(W2,W1) RY(t6,W1)   -> returns <Z_W1>, <X_W1>
// RY convention matches reference: new0 = c*s0 - s*s1; new1 = s*s0 + c*s1.

template<int M>
__device__ __forceinline__ void ry16(float* a, float c, float s) {
#pragma unroll
    for (int i = 0; i < 16; ++i)
        if (!(i & M)) {
            int j = i | M;
            float x0 = a[i], x1 = a[j];
            a[i] = c * x0 - s * x1;
            a[j] = s * x0 + c * x1;
        }
}
template<int MC, int MT>
__device__ __forceinline__ void cx16(float* a) {
#pragma unroll
    for (int i = 0; i < 16; ++i)
        if ((i & MC) && !(i & MT)) {
            int j = i | MT;
            float t = a[i]; a[i] = a[j]; a[j] = t;
        }
}

template<bool BTYPE>
__device__ __forceinline__ void sub16(const float* ic, const float* is,
                                      const float* thc, const float* ths,
                                      float& z, float& x) {
    float a[16];
    a[0] = ic[3]; a[1] = is[3];
#pragma unroll
    for (int i = 0; i < 2; ++i) { a[i | 2] = a[i] * is[2]; a[i] *= ic[2]; }
#pragma unroll
    for (int i = 0; i < 4; ++i) { a[i | 4] = a[i] * is[1]; a[i] *= ic[1]; }
#pragma unroll
    for (int i = 0; i < 8; ++i) { a[i | 8] = a[i] * is[0]; a[i] *= ic[0]; }
    ry16<8>(a, thc[0], ths[0]);
    ry16<4>(a, thc[1], ths[1]);
    cx16<8, 4>(a);
    ry16<2>(a, thc[2], ths[2]);
    ry16<1>(a, thc[3], ths[3]);
    cx16<1, 2>(a);
    ry16<4>(a, thc[4], ths[4]);
    ry16<2>(a, thc[5], ths[5]);
    if (BTYPE) { cx16<2, 4>(a); ry16<4>(a, thc[6], ths[6]); }
    else       { cx16<4, 2>(a); ry16<2>(a, thc[6], ths[6]); }
    const int m = BTYPE ? 4 : 2;
    z = 0.f; x = 0.f;
#pragma unroll
    for (int i = 0; i < 16; ++i) z += (i & m) ? -a[i] * a[i] : a[i] * a[i];
    if (BTYPE) {
#pragma unroll
        for (int i = 0; i < 16; ++i) if (!(i & 4)) x += a[i] * a[i | 4];
        x *= 2.f;
    }
}

// Per-node edge-circuit publishes: zA = <Z2> of A'(h,x0,x1,x2) [used when node
// is SENDER], (zB,xB) = <Z5>,<X5> of B'(h,x0,x1,x2) [used when node is RECV].
// teC/teS: half-angle trig of edge thetas, indices 0..13 used.
__device__ __forceinline__ void edge_pub(
        float chh, float shh, const float* cxv, const float* sxv,
        const float* teC, const float* teS,
        float& zA, float& zB, float& xB) {
    float ic[4] = {chh, cxv[0], cxv[1], cxv[2]};
    float is[4] = {shh, sxv[0], sxv[1], sxv[2]};
    float dmy;
    {   // A': thetas te{0,1,2,3,8,9,12}, measure Z on W2
        float thc[7] = {teC[0], teC[1], teC[2], teC[3], teC[8], teC[9], teC[12]};
        float ths[7] = {teS[0], teS[1], teS[2], teS[3], teS[8], teS[9], teS[12]};
        sub16<false>(ic, is, thc, ths, zA, dmy);
    }
    {   // B': thetas te{4,5,6,7,10,11,13}, measure Z,X on W1
        float thc[7] = {teC[4], teC[5], teC[6], teC[7], teC[10], teC[11], teC[13]};
        float ths[7] = {teS[4], teS[5], teS[6], teS[7], teS[10], teS[11], teS[13]};
        sub16<true>(ic, is, thc, ths, zB, xB);
    }
}

// ---------------- setup: H0 + pub0 + indices + deg + theta trig ------------
// One float4-pair per thread (2M threads): HBM-bound scan of Ri/Ro (64 MB).
// Node-init work (tid<2048) hides under the scan. Zero region pre-memset.
__global__ __launch_bounds__(256) void k_setup(
        const float* __restrict__ X, const float* __restrict__ Ri,
        const float* __restrict__ Ro, const float* __restrict__ W,
        const float* __restrict__ b, const float* __restrict__ te,
        const float* __restrict__ tn,
        int* __restrict__ send, int* __restrict__ recv, float* __restrict__ H,
        float* __restrict__ pub, float* __restrict__ trig,
        int* __restrict__ deg) {
    int tid = blockIdx.x * blockDim.x + threadIdx.x;
    if (tid < N_NODES) {
        float x0 = X[tid*3+0], x1 = X[tid*3+1], x2 = X[tid*3+2];
        float z = x0*W[0] + x1*W[1] + x2*W[2] + b[0];
        float sg = 1.0f / (1.0f + __expf(-z));
        float h = sg * TWO_PI_F;
        ((float4*)H)[tid] = make_float4(h, x0, x1, x2);
        float chh, shh, cxv[3], sxv[3];
        __sincosf(0.5f*h,  &shh, &chh);
        __sincosf(0.5f*x0, &sxv[0], &cxv[0]);
        __sincosf(0.5f*x1, &sxv[1], &cxv[1]);
        __sincosf(0.5f*x2, &sxv[2], &cxv[2]);
        float teC[14], teS[14];
#pragma unroll
        for (int k = 0; k < 14; ++k) __sincosf(0.5f*te[k], &teS[k], &teC[k]);
        float zA, zB, xB;
        edge_pub(chh, shh, cxv, sxv, teC, teS, zA, zB, xB);
        pub[tid*4+0] = zA; pub[tid*4+1] = zB; pub[tid*4+2] = xB;
    }
    if (tid >= 4096 && tid < 4096 + 15) {        // edge theta trig table
        int i = tid - 4096; float s, c;
        __sincosf(0.5f * te[i], &s, &c);
        trig[i] = c; trig[16 + i] = s;
    }
    if (tid >= 4224 && tid < 4224 + 23) {        // node theta trig table
        int i = tid - 4224; float s, c;
        __sincosf(0.5f * tn[i], &s, &c);
        trig[32 + i] = c; trig[56 + i] = s;
    }
    const float4 vi = ((const float4*)Ri)[tid];
    const float4 vo = ((const float4*)Ro)[tid];
    int base = tid * 4;
    int n = base >> 12;             // row (E = 4096)
    int e = base & (N_EDGES - 1);   // col
    int cnt = 0;
    if (vi.x != 0.f) { recv[e+0] = n; ++cnt; }
    if (vi.y != 0.f) { recv[e+1] = n; ++cnt; }
    if (vi.z != 0.f) { recv[e+2] = n; ++cnt; }
    if (vi.w != 0.f) { recv[e+3] = n; ++cnt; }
    if (vo.x != 0.f) { send[e+0] = n; ++cnt; }
    if (vo.y != 0.f) { send[e+1] = n; ++cnt; }
    if (vo.z != 0.f) { send[e+2] = n; ++cnt; }
    if (vo.w != 0.f) { send[e+3] = n; ++cnt; }
    if (cnt) atomicAdd(&deg[n], cnt);   // deg[n] = indeg + outdeg
}

// edge scatter: mi[ri] += ev*H[si], mo[si] += ev*H[ri]; then drain own vmem
// queue (atomics performed at coherence point) and tick both arrival counters.
__device__ __forceinline__ void scatter8(float ev, const float4& Hs, const float4& Hr,
                                         int si, int ri,
                                         float* __restrict__ macc, int* __restrict__ arr) {
    atomicAdd(&macc[ri*8+0], ev*Hs.x); atomicAdd(&macc[ri*8+1], ev*Hs.y);
    atomicAdd(&macc[ri*8+2], ev*Hs.z); atomicAdd(&macc[ri*8+3], ev*Hs.w);
    atomicAdd(&macc[si*8+4], ev*Hr.x); atomicAdd(&macc[si*8+5], ev*Hr.y);
    atomicAdd(&macc[si*8+6], ev*Hr.z); atomicAdd(&macc[si*8+7], ev*Hr.w);
    asm volatile("s_waitcnt vmcnt(0)" ::: "memory");
    atomicAdd(&arr[ri], 1); atomicAdd(&arr[si], 1);
}

// ---------------- persistent mega-kernel: role-specialized dataflow --------
// 96 blocks x 64 thr: blocks 0..63 = edge lanes (4096 edges), 64..95 = node
// lanes (2048 nodes). Factorized math:
//   ev   = (1 - (cos(te14)*zA[si]*zB[ri] - sin(te14)*xB[ri])) / 2
//   <Z9> = (cos(tn20)*zA1*zA2 - sin(tn20)*xA2) * zB9 ;  h = pi*(1-<Z9>)
// Sync: arr/deg (edge->node), epoch + agent pub/H (node->edge). No barriers.
__global__ __launch_bounds__(64) void k_mega(
        float* __restrict__ H, float* __restrict__ pub,
        const int* __restrict__ send, const int* __restrict__ recv,
        const float* __restrict__ trig,
        float* __restrict__ maccA, float* __restrict__ maccB,
        int* __restrict__ arrA, int* __restrict__ arrB,
        int* __restrict__ epoch, const int* __restrict__ deg,
        float* __restrict__ out) {
    int lane = threadIdx.x;
    int blk  = blockIdx.x;

    if (blk < 64) {
        // ================= EDGE thread: e = blk*64 + lane =================
        int e = blk * 64 + lane;
        int si = send[e], ri = recv[e];
        float4 Hs = ((const float4*)H)[si];    // h0 + static x's
        float4 Hr = ((const float4*)H)[ri];
        float c14 = trig[14], s14 = trig[30];
        float C14 = c14*c14 - s14*s14;         // cos(te14) from half-angle
        float S14 = 2.f*c14*s14;               // sin(te14)

        // it 0: pub from k_setup (kernel boundary -> plain loads fine)
        float zA = pub[si*4+0], zB = pub[ri*4+1], xB = pub[ri*4+2];
        float ev = 0.5f*(1.f - (C14*zA*zB - S14*xB));
        scatter8(ev, Hs, Hr, si, ri, maccA, arrA);

        // it 1: wait endpoint nodes, reload mutable scalars agent-scope
        spin_ge(epoch + si, 1); spin_ge(epoch + ri, 1);
        zA = agent_load(&pub[si*4+0]);
        zB = agent_load(&pub[ri*4+1]);
        xB = agent_load(&pub[ri*4+2]);
        Hs.x = agent_load(&H[si*4]);
        Hr.x = agent_load(&H[ri*4]);
        ev = 0.5f*(1.f - (C14*zA*zB - S14*xB));
        scatter8(ev, Hs, Hr, si, ri, maccB, arrB);

        // final: ev -> out
        spin_ge(epoch + si, 2); spin_ge(epoch + ri, 2);
        zA = agent_load(&pub[si*4+0]);
        zB = agent_load(&pub[ri*4+1]);
        xB = agent_load(&pub[ri*4+2]);
        out[e] = 0.5f*(1.f - (C14*zA*zB - S14*xB));
    } else {
        // ================= NODE thread: n = (blk-64)*64 + lane =============
        int n = (blk - 64) * 64 + lane;
        float4 Hn = ((const float4*)H)[n];
        float chh, shh, cxv[3], sxv[3];
        __sincosf(0.5f*Hn.x, &shh, &chh);       // h state (updated in regs)
        __sincosf(0.5f*Hn.y, &sxv[0], &cxv[0]); // static x trig
        __sincosf(0.5f*Hn.z, &sxv[1], &cxv[1]);
        __sincosf(0.5f*Hn.w, &sxv[2], &cxv[2]);
        int dg = deg[n];
        const float* teC = trig;      const float* teS = trig + 16;
        const float* tnC = trig + 32; const float* tnS = trig + 56;
        float C20 = tnC[20]*tnC[20] - tnS[20]*tnS[20];
        float S20 = 2.f*tnC[20]*tnS[20];

        for (int it = 0; it < 2; ++it) {
            const float* mc_ = it ? maccB : maccA;
            const int*   ar  = it ? arrB  : arrA;
            spin_ge(ar + n, dg);                 // all my edges scattered
            float M[8], mC[8], mS[8];
#pragma unroll
            for (int k = 0; k < 8; ++k) M[k] = agent_load(mc_ + n*8 + k);
#pragma unroll
            for (int k = 0; k < 8; ++k) __sincosf(0.5f*M[k], &mS[k], &mC[k]);
            float zA1, zA2, xA2, zB9, dmy;
            {   // A1 (mi, wires 0-3): tn{0,1,2,3,12,13,18}, <Z2>
                float thc[7] = {tnC[0],tnC[1],tnC[2],tnC[3],tnC[12],tnC[13],tnC[18]};
                float ths[7] = {tnS[0],tnS[1],tnS[2],tnS[3],tnS[12],tnS[13],tnS[18]};
                sub16<false>(&mC[0], &mS[0], thc, ths, zA1, dmy);
            }
            {   // A2 (mo, wires 4-7): tn{4,5,6,7,14,15,19}, <Z5>,<X5>
                float thc[7] = {tnC[4],tnC[5],tnC[6],tnC[7],tnC[14],tnC[15],tnC[19]};
                float ths[7] = {tnS[4],tnS[5],tnS[6],tnS[7],tnS[14],tnS[15],tnS[19]};
                sub16<true>(&mC[4], &mS[4], thc, ths, zA2, xA2);
            }
            {   // B (H[n], wires 8-11): tn{8,9,10,11,16,17,21}, <Z9>
                float ic[4] = {chh, cxv[0], cxv[1], cxv[2]};
                float is[4] = {shh, sxv[0], sxv[1], sxv[2]};
                float thc[7] = {tnC[8],tnC[9],tnC[10],tnC[11],tnC[16],tnC[17],tnC[21]};
                float ths[7] = {tnS[8],tnS[9],tnS[10],tnS[11],tnS[16],tnS[17],tnS[21]};
                sub16<true>(ic, is, thc, ths, zB9, dmy);
            }
            float p9 = (C20*zA1*zA2 - S20*xA2) * zB9;
            float h = PI_F * (1.f - p9);
            __sincosf(0.5f*h, &shh, &chh);
            float zAe, zBe, xBe;
            edge_pub(chh, shh, cxv, sxv, teC, teS, zAe, zBe, xBe);
            agent_store(&pub[n*4+0], zAe);
            agent_store(&pub[n*4+1], zBe);
            agent_store(&pub[n*4+2], xBe);
            agent_store(&H[n*4], h);
            asm volatile("s_waitcnt vmcnt(0)" ::: "memory");   // visible...
            agent_store_i(epoch + n, it + 1);                  // ...before tick
        }
    }
}

extern "C" void kernel_launch(void* const* d_in, const int* in_sizes, int n_in,
                              void* d_out, int out_size, void* d_ws, size_t ws_size,
                              hipStream_t stream) {
    const float* X  = (const float*)d_in[0];
    const float* Ri = (const float*)d_in[1];
    const float* Ro = (const float*)d_in[2];
    const float* W  = (const float*)d_in[3];
    const float* b  = (const float*)d_in[4];
    const float* te = (const float*)d_in[5];
    const float* tn = (const float*)d_in[6];
    float* out = (float*)d_out;

    int*   send  = (int*)d_ws;                      // [4096]
    int*   recv  = send + N_EDGES;                  // [4096]
    float* H     = (float*)(recv + N_EDGES);        // [8192]  (16B-aligned)
    float* pub   = H + N_NODES * 4;                 // [8192]  zA,zB,xB,- per node
    float* trig  = pub + N_NODES * 4;               // [128]
    // ---- zero region (one memset, stream-ordered before k_setup) ----
    float* maccA = trig + 128;                      // [16384]
    float* maccB = maccA + N_NODES * 8;             // [16384]
    int*   arrA  = (int*)(maccB + N_NODES * 8);     // [2048]
    int*   arrB  = arrA + N_NODES;                  // [2048]
    int*   epoch = arrB + N_NODES;                  // [2048]
    int*   deg   = epoch + N_NODES;                 // [2048]
    size_t zbytes = (size_t)(2 * N_NODES * 8 + 4 * N_NODES) * sizeof(float);

    hipMemsetAsync((void*)maccA, 0, zbytes, stream);
    int total4 = (N_NODES * N_EDGES) / 4;           // one float4-pair per thread
    k_setup<<<total4 / 256, 256, 0, stream>>>(X, Ri, Ro, W, b, te, tn,
                                              send, recv, H, pub, trig, deg);
    k_mega<<<96, 64, 0, stream>>>(H, pub, send, recv, trig,
                                  maccA, maccB, arrA, arrB, epoch, deg, out);
}